// Round 7
// baseline (323.875 us; speedup 1.0000x reference)
//
#include <hip/hip_runtime.h>

// Problem constants (fixed by reference setup_inputs)
#define NB 8
#define NA 3
#define NH 160
#define NW 160
#define NCLS 80
#define NGT 32
#define NPB (NA * NH * NW)        // 76,800 cells per batch
#define TOTAL (NB * NPB)          // 614,400 cells
#define BLK 128                   // 2 waves per block (barrier-free design)
#define NBLK (TOTAL / BLK)        // 4800 blocks; NPB % 128 == 0
#define TOTALF4 (TOTAL * 20)      // 12,288,000 float4 in cls_logits
// Output: ONE flat float32 buffer, outputs concatenated in return order:
// p_bbox [8,76800,4] | cls_idx [8,76800] | score [8,76800] | loss [1]
#define OFF_CLSIDX (TOTAL * 4)    // 2,457,600  (f32 elements)
#define OFF_SCORE  (TOTAL * 5)    // 3,072,000
#define OFF_LOSS   (TOTAL * 6)    // 3,686,400

#define F4_PER_ROW 20             // 80 classes = 20 float4 per cell

// Loss accumulator slots, 64B-spaced (9600 wave-atomics spread over 8 lines).
// INVARIANT: all-zero on kernel entry; det_fin_k sums and re-zeros each
// replay. NO device fences anywhere (round-1 lesson: ~90 us). Kernel
// boundary = coherence.
__device__ float g_acc[8 * 16];   // slot s at [s*16]

// Round-6 lesson: rcpf bought 0 measurable us and doubled absmax (loss is
// ~5e4 magnitude; 1e-5 rel perturbation -> 0.5 abs). IEEE div everywhere.
__device__ __forceinline__ float det_sigmoid(float x) { return 1.0f / (1.0f + expf(-x)); }
__device__ __forceinline__ float det_bce(float x, float t) {
    return fmaxf(x, 0.0f) - x * t + log1pf(expf(-fabsf(x)));
}
__device__ __forceinline__ float det_aw3(int a) { return a == 0 ? 10.0f : (a == 1 ? 16.0f : 33.0f); }
__device__ __forceinline__ float det_ah3(int a) { return a == 0 ? 13.0f : (a == 1 ? 30.0f : 23.0f); }

// gt_mask layout detection (u8 bool vs int32), deterministic each call.
__device__ __forceinline__ bool det_mask_is_u8(const void* p) {
    const unsigned int* w = (const unsigned int*)p;
    unsigned int acc = 0;
#pragma unroll
    for (int k = 0; k < 64; k++) acc |= (w[k] & 0xFFFFFF00u);
    return acc != 0;
}
__device__ __forceinline__ bool det_mask_at(const void* p, bool u8mode, int idx) {
    return u8mode ? (((const unsigned char*)p)[idx] != 0)
                  : (((const int*)p)[idx] != 0);
}

// Per-(b,g) target losses (xy, wh, cls) — one (b,g) pair per thread.
// Blocks 0..1 cover gtid = blockIdx.x*128 + tid in [0,256) = 8 batches x 32.
// (Verified correct rounds 1-6.)
__device__ __forceinline__ float det_gt_loss(int gtid,
        const float* __restrict__ t_bbox,
        const float* __restrict__ cls_logits,
        const float* __restrict__ gt_bboxes,
        const int* __restrict__ gt_cls,
        const void* __restrict__ gt_mask) {
    bool u8mode = det_mask_is_u8(gt_mask);
    int b = gtid >> 5;
    int g = gtid & 31;
    float4 gtb = ((const float4*)gt_bboxes)[b * NGT + g];
    float cx = gtb.x, cy = gtb.y, gw = gtb.z, gh = gtb.w;

    const float aw9[9] = {10.f,16.f,33.f,30.f,62.f,59.f,116.f,156.f,373.f};
    const float ah9[9] = {13.f,30.f,23.f,61.f,45.f,119.f,90.f,198.f,326.f};
    float garea = gw * gh;
    int aidx = 0;
    float best = -1.0f;
#pragma unroll
    for (int k = 0; k < 9; k++) {
        float inter = fminf(gw, aw9[k]) * fminf(gh, ah9[k]);
        float uni = garea + aw9[k] * ah9[k] - inter;
        float r = inter / (uni + 1e-16f);
        if (r > best) { best = r; aidx = k; }
    }
    bool valid = det_mask_at(gt_mask, u8mode, b * NGT + g) && (aidx < NA);
    int ta = aidx % NA;
    int ti = min(max((int)(cx * 0.125f), 0), NW - 1);
    int tj = min(max((int)(cy * 0.125f), 0), NH - 1);
    size_t cell = ((size_t)(b * NA + ta) * NH + tj) * NW + ti;

    float4 tb = ((const float4*)t_bbox)[cell];
    float fx = cx * 0.125f; fx -= floorf(fx);
    float fy = cy * 0.125f; fy -= floorf(fy);
    float tx = (fx + 0.5f) * 0.5f;
    float ty = (fy + 0.5f) * 0.5f;
    float tw = sqrtf(gw / det_aw3(ta)) * 0.5f;
    float th = sqrtf(gh / det_ah3(ta)) * 0.5f;

    float l = det_bce(tb.x, tx) + det_bce(tb.y, ty) +
              det_bce(tb.z, tw) + det_bce(tb.w, th);

    const float4* cl = (const float4*)(cls_logits + cell * NCLS);
    int tc = gt_cls[b * NGT + g];
    float lc = 0.0f;
#pragma unroll
    for (int c4 = 0; c4 < NCLS / 4; c4++) {
        float4 v = cl[c4];
        int c = c4 * 4;
        lc += det_bce(v.x, (c + 0 == tc) ? 1.0f : 0.0f);
        lc += det_bce(v.y, (c + 1 == tc) ? 1.0f : 0.0f);
        lc += det_bce(v.z, (c + 2 == tc) ? 1.0f : 0.0f);
        lc += det_bce(v.w, (c + 3 == tc) ? 1.0f : 0.0f);
    }
    l += lc * (1.0f / NCLS);
    return valid ? l : 0.0f;
}

// ---------------- Main fused kernel ----------------------------------------
// ROUND-7 — LDS-free phase 2 via 20-lane-group shuffle reduce:
//   History: r3 GLDS-dbuf ~93us == r6 (1-wave, 14 w/CU); r4 drain-per-tile
//   regressed; r5 strided-global regressed 2.5x. All LDS-staged variants are
//   latency-bound with occupancy capped by the 10 KB/wave double buffer.
//   Key fact r5 missed: a COALESCED dwordx4 load at f4 = rowbase*20 + lane
//   already delivers 3 complete 80-class rows to contiguous 20-lane groups
//   (row r+g in lanes [20g,20g+20), class-quad j at lane 20g+j). Row argmax
//   is then a 5-step __shfl_down segmented reduce — no LDS tile at all:
//   no DMA, no waitcnt choreography, 22 independent load->reduce chains the
//   compiler pipelines freely. LDS ~1.6 KB => occupancy VGPR-bound:
//   launch_bounds(128,6) -> 24 waves/CU (1.7x r6) with better ILP.
//   2-wave blocks + PER-WAVE GT staging copies => still zero barriers.
__global__ __launch_bounds__(128, 6) void det_all_k(
    const float* __restrict__ t_bbox,
    const float* __restrict__ conf_logits,
    const float* __restrict__ cls_logits,
    const float* __restrict__ gt_bboxes,
    const int* __restrict__ gt_cls,
    const void* __restrict__ gt_mask,
    float* __restrict__ out) {
    __shared__ float4 s_box[2][NGT];   // per-wave copies: no cross-wave sync
    __shared__ float2 s_am[2][NGT];

    int tid = threadIdx.x;
    int wv  = tid >> 6;                  // wave 0/1
    int l   = tid & 63;                  // lane
    int blockCellW = blockIdx.x * BLK + wv * 64;   // this wave's 64 cells
    int gid = blockCellW + l;
    int b = gid / NPB;                   // uniform within a block (128|NPB)
    int r = gid % NPB;

    // GT staging: lanes 0..31 of EACH wave write that wave's copy; all lanes
    // of the same wave read later. Same-wave DS ops execute in program order
    // -> no barrier needed (r6-validated structure).
    if (l < NGT) {
        bool u8mode = det_mask_is_u8(gt_mask);
        float4 gtb = ((const float4*)gt_bboxes)[b * NGT + l];
        float4 bx;
        bx.x = gtb.x - gtb.z * 0.5f;   // x1
        bx.y = gtb.y - gtb.w * 0.5f;   // y1
        bx.z = gtb.x + gtb.z * 0.5f;   // x2
        bx.w = gtb.y + gtb.w * 0.5f;   // y2
        s_box[wv][l] = bx;
        float2 am;
        am.x = gtb.z * gtb.w;
        am.y = det_mask_at(gt_mask, u8mode, b * NGT + l) ? 1.0f : 0.0f;
        s_am[wv][l] = am;
    }

    // ---- Phase 1: bbox decode + IoU + conf BCE ----
    int a   = r / (NH * NW);
    int rem = r % (NH * NW);
    int j   = rem / NW;
    int i   = rem % NW;

    float4 tb = ((const float4*)t_bbox)[gid];
    float confl = conf_logits[gid];
    float s0 = det_sigmoid(tb.x), s1 = det_sigmoid(tb.y);
    float s2 = det_sigmoid(tb.z), s3 = det_sigmoid(tb.w);
    float px = (s0 * 2.0f - 0.5f + (float)i) * 8.0f;
    float py = (s1 * 2.0f - 0.5f + (float)j) * 8.0f;
    float sw = s2 * 2.0f, sh = s3 * 2.0f;
    float pw = sw * sw * det_aw3(a);
    float ph = sh * sh * det_ah3(a);
    float4 pb; pb.x = px; pb.y = py; pb.z = pw; pb.w = ph;
    ((float4*)out)[gid] = pb;

    float px1 = px - pw * 0.5f, px2 = px + pw * 0.5f;
    float py1 = py - ph * 0.5f, py2 = py + ph * 0.5f;
    float parea = pw * ph;
    float maxiou = 0.0f;
#pragma unroll
    for (int g = 0; g < NGT; g++) {
        float4 bx = s_box[wv][g];
        float2 am = s_am[wv][g];
        float iw = fmaxf(fminf(px2, bx.z) - fmaxf(px1, bx.x), 0.0f);
        float ih = fmaxf(fminf(py2, bx.w) - fmaxf(py1, bx.y), 0.0f);
        float inter = iw * ih;
        float uni = parea + am.x - inter;
        float iou = inter / (uni + 1e-16f);
        maxiou = fmaxf(maxiou, (am.y != 0.0f) ? iou : 0.0f);
    }

    float sconf = det_sigmoid(confl);          // reused in phase 2 via shfl
    float lconf = det_bce(confl, maxiou);

    // Blocks 0..1 carry the 256 GT target losses (gtid = bid*128 + tid).
    if (blockIdx.x < 2)
        lconf += det_gt_loss(blockIdx.x * BLK + tid,
                             t_bbox, cls_logits, gt_bboxes, gt_cls, gt_mask);

#pragma unroll
    for (int off = 32; off > 0; off >>= 1) lconf += __shfl_down(lconf, off, 64);
    // lane 0 of each wave holds the wave total; atomic issued at kernel end.

    // ---- Phase 2: class argmax + score, LDS-free shuffle reduce ----
    // Lane l = 20*g_ + jj. Load t covers rows 3t..3t+2 of this wave's 64:
    // f4 index (blockCellW + 3t)*20 + l is CONSECUTIVE across the wave ->
    // one coalesced dwordx4; lanes 60-63 load don't-care (discarded).
    // 22 iterations cover rows 0..63 (t=21 covers row 63 in group 0).
    {
        int g_ = l / 20;                 // 0..2 real groups; 3 = discard lanes
        int jj = l - g_ * 20;            // class-quad position within row
        const float4* g4 = (const float4*)cls_logits;
#pragma unroll
        for (int t = 0; t < 22; ++t) {
            int rr = 3 * t + g_;         // row within this wave's 64 cells
            int f4i = (blockCellW + 3 * t) * F4_PER_ROW + l;
            f4i = min(f4i, TOTALF4 - 1);          // tail clamp (last block)
            float4 v = g4[f4i];

            int cb = jj * 4;                       // first class of this quad
            float mx = v.x; int mi = cb;
            if (v.y > mx) { mx = v.y; mi = cb + 1; }
            if (v.z > mx) { mx = v.z; mi = cb + 2; }
            if (v.w > mx) { mx = v.w; mi = cb + 3; }

            // segmented 20-lane reduce; lexicographic (value, lower index)
            // == jnp first-max. Cross-group merges predicated off.
#pragma unroll
            for (int off = 1; off < 20; off <<= 1) {   // 1,2,4,8,16
                float ov = __shfl_down(mx, off, 64);
                int   oi = __shfl_down(mi, off, 64);
                if ((jj + off < 20) &&
                    (ov > mx || (ov == mx && oi < mi))) { mx = ov; mi = oi; }
            }
            // sigmoid(conf) of row rr lives in lane rr of this wave (phase 1)
            float sc = __shfl(sconf, rr & 63, 64);
            if (jj == 0 && g_ < 3 && rr < 64) {    // 3 lanes store 3 consecutive cells
                int cellg = blockCellW + rr;
                out[OFF_CLSIDX + cellg] = (float)mi;
                out[OFF_SCORE  + cellg] = sc * det_sigmoid(mx);
            }
        }
    }

    // ---- Epilogue: wave total -> spread atomic slot ------------------------
    if (l == 0)
        atomicAdd(&g_acc[((blockIdx.x * 2 + wv) & 7) * 16], lconf);
}

// ---------------- Finalize: sum slots, write loss, reset -------------------
__global__ void det_fin_k(float* __restrict__ out) {
    float tot = 0.0f;
#pragma unroll
    for (int s = 0; s < 8; ++s) { tot += g_acc[s * 16]; g_acc[s * 16] = 0.0f; }
    out[OFF_LOSS] = tot * (1.0f / NB);
}

extern "C" void kernel_launch(void* const* d_in, const int* in_sizes, int n_in,
                              void* d_out, int out_size, void* d_ws, size_t ws_size,
                              hipStream_t stream) {
    (void)in_sizes; (void)n_in; (void)out_size; (void)d_ws; (void)ws_size;
    const float* t_bbox      = (const float*)d_in[0];
    const float* conf_logits = (const float*)d_in[1];
    const float* cls_logits  = (const float*)d_in[2];
    const float* gt_bboxes   = (const float*)d_in[3];
    const int*   gt_cls      = (const int*)d_in[4];
    const void*  gt_mask     = (const void*)d_in[5];  // layout auto-detected
    float* out = (float*)d_out;                       // float32 per reference

    det_all_k<<<NBLK, BLK, 0, stream>>>(t_bbox, conf_logits, cls_logits,
                                        gt_bboxes, gt_cls, gt_mask, out);
    det_fin_k<<<1, 1, 0, stream>>>(out);
}